// Round 16
// baseline (137.366 us; speedup 1.0000x reference)
//
#include <hip/hip_runtime.h>
#include <hip/hip_bf16.h>

#define B_DIM 8192
#define D_DIM 256
#define GRID_GEMM 256
#define NT 16   // 32-col tiles per block (512 cols per block)

constexpr float INV_T  = 14.285714285714286f;   // 1/0.07; the logsumexp shift M
// q pre-scaled by INV_T*log2(e): acc = z*log2(e); exp(z-M) = exp2(acc - QS)
constexpr float QSCALE = 20.609929155556605f;   // INV_T * log2(e)
constexpr float LN2F   = 0.6931471805599453f;

typedef __bf16 bf16x8 __attribute__((ext_vector_type(8)));
typedef float  f32x4  __attribute__((ext_vector_type(4)));

#define GLOBAL_U32(p) ((const __attribute__((address_space(1))) unsigned int*)(p))
#define LDS_U32(p)    ((__attribute__((address_space(3))) unsigned int*)(p))

// s_waitcnt imm (gfx9): vm[3:0]=bits3:0, exp=bits6:4, lgkm=bits11:8, vm[5:4]=bits15:14
// vmcnt(8), expcnt/lgkmcnt = no-wait:
#define WAITCNT_VM8 0x0F78

__device__ inline unsigned short f2bf(float f) {
    union { float f; unsigned u; } x; x.f = f;
    unsigned r = x.u + 0x7fffu + ((x.u >> 16) & 1u);  // RNE
    return (unsigned short)(r >> 16);
}

// Kernel 1: q = normalize(h+r) * QSCALE, t = normalize(t); BOTH stored in
// 16x16x32-MFMA FRAGMENT order: 16B-slot ((row>>4)*8 + (k>>5))*64 +
// ((k>>3)&3)*16 + (row&15) holds k-run [k&~7 .. +8). GEMM lane l reads
// slot (l>>4)*16 + (l&15): row=(l&15), k-run=(l>>4) -- coalesced 1KB/inst.
// (verified R13/R15). Block 0 additionally zeroes rowsum/diagsum/ticket.
__global__ __launch_bounds__(256) void norm_kernel(
    const float* __restrict__ h, const float* __restrict__ r,
    const float* __restrict__ t,
    unsigned short* __restrict__ qws, unsigned short* __restrict__ tws,
    float* __restrict__ rowsum, float* __restrict__ diagsum, int* __restrict__ ticket)
{
    if (blockIdx.x == 0) {
        float4* rs4 = (float4*)rowsum;
#pragma unroll
        for (int i = 0; i < 8; ++i)
            rs4[threadIdx.x * 8 + i] = make_float4(0.f, 0.f, 0.f, 0.f);
        if (threadIdx.x == 0) { *diagsum = 0.f; *ticket = 0; }
    }

    const int wave = threadIdx.x >> 6;
    const int lane = threadIdx.x & 63;
    const int wg   = blockIdx.x * 4 + wave;      // 0..4095, 2 rows each

    // fragment store coords for this lane (k = 4*lane + j'):
    const int kst  = lane >> 3;          // k>>5
    const int krun = (lane >> 1) & 3;    // (k>>3)&3
    const int sub8 = lane & 1;           // (k>>2)&1 within the 8-run

#pragma unroll
    for (int i = 0; i < 2; ++i) {
        const int row = wg * 2 + i;              // 0..8191
        const size_t slot16 = ((size_t)((row >> 4) * 8 + kst) * 64
                               + (size_t)(krun * 16 + (row & 15)));
        // ---- q = normalize(h+r) * QSCALE ----
        {
            float4 a = ((const float4*)h)[row * 64 + lane];
            float4 b = ((const float4*)r)[row * 64 + lane];
            float4 v = make_float4(a.x + b.x, a.y + b.y, a.z + b.z, a.w + b.w);
            float s = v.x * v.x + v.y * v.y + v.z * v.z + v.w * v.w;
#pragma unroll
            for (int off = 32; off; off >>= 1) s += __shfl_xor(s, off, 64);
            float scale = QSCALE / fmaxf(sqrtf(s), 1e-12f);
            ushort4 o;
            o.x = f2bf(v.x * scale); o.y = f2bf(v.y * scale);
            o.z = f2bf(v.z * scale); o.w = f2bf(v.w * scale);
            *(ushort4*)((unsigned char*)qws + slot16 * 16 + sub8 * 8) = o;
        }
        // ---- t = normalize(t) ----
        {
            float4 v = ((const float4*)t)[row * 64 + lane];
            float s = v.x * v.x + v.y * v.y + v.z * v.z + v.w * v.w;
#pragma unroll
            for (int off = 32; off; off >>= 1) s += __shfl_xor(s, off, 64);
            float scale = 1.0f / fmaxf(sqrtf(s), 1e-12f);
            ushort4 o;
            o.x = f2bf(v.x * scale); o.y = f2bf(v.y * scale);
            o.z = f2bf(v.z * scale); o.w = f2bf(v.w * scale);
            *(ushort4*)((unsigned char*)tws + slot16 * 16 + sub8 * 8) = o;
        }
    }
}

// Kernel 2: R15's verified deep-prefetch skeleton (512-thread block, 1/CU,
// ring-8 x 16 KB = 128 KB, prefetch distance 3 pairs, counted vmcnt(8),
// one barrier per round) + the register budget that config unlocks:
// occupancy is LDS-pinned at 2 waves/SIMD, so up to 256 VGPR/wave is free
// (R15 used 124). (1) T15 deferred epilogue, funded this time (R1's attempt
// spilled at the old ~128-reg budget): two named acc sets accE/accO; tile
// t's exp+diag sits after tile t+1's MFMA block, so its VALU interleaves
// into the MFMA region (separate pipes). The last odd tile's epilogue
// legally crosses the barrier. (2) exp2 path: q pre-scaled by INV_T*log2e,
// epilogue = exp2f(acc - QSCALE) -> v_exp_f32 native, one v_mul/element
// saved; diag converts once via ln2. MFMA/layout = R13/R15 verbatim.
__global__ __launch_bounds__(512, 2) void gemm_lse_kernel(
    const unsigned char* __restrict__ qws, const unsigned char* __restrict__ tws,
    float* __restrict__ rowsum, float* __restrict__ diagsum,
    int* __restrict__ ticket, float* __restrict__ out)
{
    __shared__ __align__(16) unsigned char ldsB[8][16384];   // 128 KB ring
    __shared__ float wred[8];
    __shared__ int lastflag;

    const int tid  = threadIdx.x;
    const int lane = tid & 63;
    const int w    = tid >> 6;               // 0..7
    const int l15  = lane & 15;
    const int hi4  = lane >> 4;

    const int cc   = blockIdx.x & 15;        // col chunk (fast -> XCD locality)
    const int rb   = blockIdx.x >> 4;        // row block 0..15
    const int row0 = rb * 512 + w * 64;      // this wave's 64 rows
    const int col0 = cc * 512;
    const int tile0 = cc * 16;               // first 32-col tile of this chunk

    // stage tile st (16 KB, fragment-order = linear) into ring buffer bufi:
    // 512 threads x 2 x 16B insts.
#define STAGE(st, bufi)                                                      \
    {                                                                        \
        const unsigned char* gs = tws + (size_t)(tile0 + (st)) * 16384;      \
        _Pragma("unroll")                                                    \
        for (int it = 0; it < 2; ++it)                                       \
            __builtin_amdgcn_global_load_lds(                                \
                GLOBAL_U32(gs + (it * 512 + tid) * 16),                      \
                LDS_U32(&ldsB[bufi][(it * 512 + tid) * 16]), 16, 0, 0);      \
    }

    // prologue: pairs 0,1,2 (tiles 0..5) in flight = 12 insts/thread
    STAGE(0, 0); STAGE(1, 1);
    STAGE(2, 2); STAGE(3, 3);
    STAGE(4, 4); STAGE(5, 5);

    // ---- A fragments in registers: rows row0..row0+63, full K=256 ----
    // frag-order qws: byte = row0*512 + r*8192 + kst*1024 + lane*16
    // -> row = row0 + r*16 + (lane&15), k-run = (lane>>4), kst = k>>5
    bf16x8 a[4][8];
    {
        const unsigned char* abase = qws + (size_t)row0 * 512 + lane * 16;
#pragma unroll
        for (int r = 0; r < 4; ++r)
#pragma unroll
            for (int kst = 0; kst < 8; ++kst)
                a[r][kst] = *(const bf16x8*)(abase + r * 8192 + kst * 1024);
    }

    float rowacc[16] = {};
    float diagacc = 0.f;
    f32x4 accE[4][2], accO[4][2];

    // MFMA for one 32-col tile t into ACC (zeroed here): 2 col-frags x
    // 8 k-steps x 4 row-frags = 64 MFMA, 8 independent chains.
#define MFMA_TILE(t, ACC)                                                    \
    {                                                                        \
        const unsigned char* bbuf = ldsB[(t) & 7] + lane * 16;               \
        _Pragma("unroll")                                                    \
        for (int r4 = 0; r4 < 4; ++r4)                                       \
            _Pragma("unroll")                                                \
            for (int cg = 0; cg < 2; ++cg)                                   \
                ACC[r4][cg] = (f32x4){};                                     \
        _Pragma("unroll")                                                    \
        for (int kst = 0; kst < 8; ++kst) {                                  \
            bf16x8 b0 = *(const bf16x8*)(bbuf + kst * 1024);                 \
            bf16x8 b1 = *(const bf16x8*)(bbuf + 8192 + kst * 1024);          \
            _Pragma("unroll")                                                \
            for (int r4 = 0; r4 < 4; ++r4) {                                 \
                ACC[r4][0] = __builtin_amdgcn_mfma_f32_16x16x32_bf16(        \
                                 a[r4][kst], b0, ACC[r4][0], 0, 0, 0);       \
                ACC[r4][1] = __builtin_amdgcn_mfma_f32_16x16x32_bf16(        \
                                 a[r4][kst], b1, ACC[r4][1], 0, 0, 0);       \
            }                                                                \
        }                                                                    \
    }

    // deferred epilogue of tile t from ACC: exp2-sum + diagonal.
#define EPI_DIAG(t, ACC)                                                     \
    {                                                                        \
        _Pragma("unroll")                                                    \
        for (int r4 = 0; r4 < 4; ++r4)                                       \
            _Pragma("unroll")                                                \
            for (int g2 = 0; g2 < 4; ++g2)                                   \
                rowacc[r4 * 4 + g2] += exp2f(ACC[r4][0][g2] - QSCALE)        \
                                     + exp2f(ACC[r4][1][g2] - QSCALE);       \
        const int c0t = col0 + (t) * 32;                                     \
        if (c0t == row0) {                                                   \
            _Pragma("unroll")                                                \
            for (int g2 = 0; g2 < 4; ++g2)                                   \
                if (l15 == hi4 * 4 + g2)                                     \
                    diagacc += ACC[0][0][g2] + ACC[1][1][g2];                \
        }                                                                    \
        if (c0t == row0 + 32) {                                              \
            _Pragma("unroll")                                                \
            for (int g2 = 0; g2 < 4; ++g2)                                   \
                if (l15 == hi4 * 4 + g2)                                     \
                    diagacc += ACC[2][0][g2] + ACC[3][1][g2];                \
        }                                                                    \
    }

    for (int r = 0; r < 8; ++r) {
        // counted wait: drain pair r (oldest 4 insts); pairs r+1, r+2
        // (8 insts) stay in flight. At r=0 this also drains the A-loads.
        __builtin_amdgcn_s_waitcnt(WAITCNT_VM8);
        __builtin_amdgcn_s_barrier();
        // stage pair r+3 into buffers (2r+6)&7,(2r+7)&7 -- last read in
        // round r-1. Tail rounds dummy-re-stage pair 7 (uniform vmcnt).
        const int p = (r + 3 < 8) ? r + 3 : 7;
        STAGE(2 * p,     (2 * r + 6) & 7);
        STAGE(2 * p + 1, (2 * r + 7) & 7);

        MFMA_TILE(2 * r, accE);
        if (r > 0) EPI_DIAG(2 * r - 1, accO);   // prev round's odd tile
        MFMA_TILE(2 * r + 1, accO);
        EPI_DIAG(2 * r, accE);                  // this round's even tile
    }
    EPI_DIAG(15, accO);                          // final odd tile

    // ---- reduce across the 16 column-lanes of each group, then atomics ----
    // rowacc[rr]: row = row0 + (rr>>2)*16 + hi4*4 + (rr&3); xor-reduce over
    // the low 4 lane bits (16 lanes share a row).
#pragma unroll
    for (int rr = 0; rr < 16; ++rr) {
        float s = rowacc[rr];
        s += __shfl_xor(s, 1, 64);
        s += __shfl_xor(s, 2, 64);
        s += __shfl_xor(s, 4, 64);
        s += __shfl_xor(s, 8, 64);
        if (l15 == 0) {
            int grow = row0 + (rr >> 2) * 16 + hi4 * 4 + (rr & 3);
            atomicAdd(&rowsum[grow], s);
        }
    }

    float dsum = diagacc * LN2F;    // acc is z*log2e -> convert to z once
#pragma unroll
    for (int off = 32; off; off >>= 1) dsum += __shfl_xor(dsum, off, 64);
    if (lane == 0 && dsum != 0.f) atomicAdd(diagsum, dsum);

    // ---- ticket: last block computes the loss ----
    __syncthreads();
    if (tid == 0) {
        __threadfence();
        int old = __hip_atomic_fetch_add(ticket, 1, __ATOMIC_ACQ_REL,
                                         __HIP_MEMORY_SCOPE_AGENT);
        lastflag = (old == GRID_GEMM - 1);
    }
    __syncthreads();
    if (!lastflag) return;

    float lsum = 0.f;
    for (int rr = tid; rr < B_DIM; rr += 512) {
        float rs = __hip_atomic_load(&rowsum[rr], __ATOMIC_RELAXED,
                                     __HIP_MEMORY_SCOPE_AGENT);
        lsum += __logf(rs);
    }
#pragma unroll
    for (int off = 32; off; off >>= 1) lsum += __shfl_xor(lsum, off, 64);
    if (lane == 0) wred[w] = lsum;
    __syncthreads();
    if (tid == 0) {
        float total = wred[0] + wred[1] + wred[2] + wred[3]
                    + wred[4] + wred[5] + wred[6] + wred[7]
                    + (float)B_DIM * INV_T   // + M per row
                    - __hip_atomic_load(diagsum, __ATOMIC_RELAXED,
                                        __HIP_MEMORY_SCOPE_AGENT);
        out[0] = total / (float)B_DIM;
    }
}

extern "C" void kernel_launch(void* const* d_in, const int* in_sizes, int n_in,
                              void* d_out, int out_size, void* d_ws, size_t ws_size,
                              hipStream_t stream)
{
    const float* h = (const float*)d_in[0];
    const float* r = (const float*)d_in[1];
    const float* t = (const float*)d_in[2];

    unsigned char* ws = (unsigned char*)d_ws;
    unsigned short* qws = (unsigned short*)ws;                        // 4 MB (frag order, pre-scaled)
    unsigned short* tws = (unsigned short*)(ws + 4u * 1024 * 1024);   // 4 MB (frag order)
    float* rowsum  = (float*)(ws + 8u * 1024 * 1024);                 // 32 KB
    float* diagsum = (float*)(ws + 8u * 1024 * 1024 + 32u * 1024);
    int*   ticket  = (int*)  (ws + 8u * 1024 * 1024 + 32u * 1024 + 16);

    norm_kernel<<<1024, 256, 0, stream>>>(h, r, t, qws, tws, rowsum, diagsum, ticket);
    gemm_lse_kernel<<<GRID_GEMM, 512, 0, stream>>>(
        (const unsigned char*)qws, (const unsigned char*)tws,
        rowsum, diagsum, ticket, (float*)d_out);
}

// Round 17
// 126.141 us; speedup vs baseline: 1.0890x; 1.0890x over previous
//
#include <hip/hip_runtime.h>
#include <hip/hip_bf16.h>

#define B_DIM 8192
#define D_DIM 256
#define GRID_GEMM 256
#define NT 16   // 32-col tiles per block (512 cols per block)

constexpr float INV_T  = 14.285714285714286f;   // 1/0.07; the logsumexp shift M
// q pre-scaled by INV_T*log2(e): acc = z*log2(e); exp(z-M) = exp2(acc - QS)
constexpr float QSCALE = 20.609929155556605f;   // INV_T * log2(e)
constexpr float LN2F   = 0.6931471805599453f;

typedef __bf16 bf16x8 __attribute__((ext_vector_type(8)));
typedef float  f32x4  __attribute__((ext_vector_type(4)));

#define GLOBAL_U32(p) ((const __attribute__((address_space(1))) unsigned int*)(p))
#define LDS_U32(p)    ((__attribute__((address_space(3))) unsigned int*)(p))

// s_waitcnt imm (gfx9): vm[3:0]=bits3:0, exp=bits6:4, lgkm=bits11:8, vm[5:4]=bits15:14
// vmcnt(8), expcnt/lgkmcnt = no-wait:
#define WAITCNT_VM8 0x0F78

__device__ inline unsigned short f2bf(float f) {
    union { float f; unsigned u; } x; x.f = f;
    unsigned r = x.u + 0x7fffu + ((x.u >> 16) & 1u);  // RNE
    return (unsigned short)(r >> 16);
}

// Kernel 1: q = normalize(h+r) * QSCALE, t = normalize(t); BOTH stored in
// 16x16x32-MFMA FRAGMENT order: 16B-slot ((row>>4)*8 + (k>>5))*64 +
// ((k>>3)&3)*16 + (row&15) holds k-run [k&~7 .. +8). GEMM lane l reads
// slot (l>>4)*16 + (l&15): row=(l&15), k-run=(l>>4) -- coalesced 1KB/inst.
// (verified R13/R15/R16). Block 0 additionally zeroes rowsum/diagsum/ticket.
__global__ __launch_bounds__(256) void norm_kernel(
    const float* __restrict__ h, const float* __restrict__ r,
    const float* __restrict__ t,
    unsigned short* __restrict__ qws, unsigned short* __restrict__ tws,
    float* __restrict__ rowsum, float* __restrict__ diagsum, int* __restrict__ ticket)
{
    if (blockIdx.x == 0) {
        float4* rs4 = (float4*)rowsum;
#pragma unroll
        for (int i = 0; i < 8; ++i)
            rs4[threadIdx.x * 8 + i] = make_float4(0.f, 0.f, 0.f, 0.f);
        if (threadIdx.x == 0) { *diagsum = 0.f; *ticket = 0; }
    }

    const int wave = threadIdx.x >> 6;
    const int lane = threadIdx.x & 63;
    const int wg   = blockIdx.x * 4 + wave;      // 0..4095, 2 rows each

    // fragment store coords for this lane (k = 4*lane + j'):
    const int kst  = lane >> 3;          // k>>5
    const int krun = (lane >> 1) & 3;    // (k>>3)&3
    const int sub8 = lane & 1;           // (k>>2)&1 within the 8-run

#pragma unroll
    for (int i = 0; i < 2; ++i) {
        const int row = wg * 2 + i;              // 0..8191
        const size_t slot16 = ((size_t)((row >> 4) * 8 + kst) * 64
                               + (size_t)(krun * 16 + (row & 15)));
        // ---- q = normalize(h+r) * QSCALE ----
        {
            float4 a = ((const float4*)h)[row * 64 + lane];
            float4 b = ((const float4*)r)[row * 64 + lane];
            float4 v = make_float4(a.x + b.x, a.y + b.y, a.z + b.z, a.w + b.w);
            float s = v.x * v.x + v.y * v.y + v.z * v.z + v.w * v.w;
#pragma unroll
            for (int off = 32; off; off >>= 1) s += __shfl_xor(s, off, 64);
            float scale = QSCALE / fmaxf(sqrtf(s), 1e-12f);
            ushort4 o;
            o.x = f2bf(v.x * scale); o.y = f2bf(v.y * scale);
            o.z = f2bf(v.z * scale); o.w = f2bf(v.w * scale);
            *(ushort4*)((unsigned char*)qws + slot16 * 16 + sub8 * 8) = o;
        }
        // ---- t = normalize(t) ----
        {
            float4 v = ((const float4*)t)[row * 64 + lane];
            float s = v.x * v.x + v.y * v.y + v.z * v.z + v.w * v.w;
#pragma unroll
            for (int off = 32; off; off >>= 1) s += __shfl_xor(s, off, 64);
            float scale = 1.0f / fmaxf(sqrtf(s), 1e-12f);
            ushort4 o;
            o.x = f2bf(v.x * scale); o.y = f2bf(v.y * scale);
            o.z = f2bf(v.z * scale); o.w = f2bf(v.w * scale);
            *(ushort4*)((unsigned char*)tws + slot16 * 16 + sub8 * 8) = o;
        }
    }
}

// Kernel 2: R15's verified deep-prefetch skeleton EXACTLY (512-thread block,
// 1/CU, ring-8 x 16 KB = 128 KB, prefetch distance 3 pairs, counted
// vmcnt(8), one barrier per round, single acc set, immediate epilogue).
// R16's deferred-epilogue spilled even at the 256-reg budget (WRITE 2->11MB)
// -- A-in-regs(128) + 2 acc sets don't fit; reverted for good. Salvaged
// register-neutral pieces: (1) exp2 path (q pre-scaled by INV_T*log2e;
// epilogue = exp2f(acc - QSCALE), one v_mul/element saved; diag converts
// once via ln2); (2) T5 s_setprio(1/0) around the MFMA block -- this deep
// pipeline has wave role-diversity between barriers (the m218b-positive
// regime, not m190's lockstep null). MFMA/layout = R13/R15 verbatim.
__global__ __launch_bounds__(512, 2) void gemm_lse_kernel(
    const unsigned char* __restrict__ qws, const unsigned char* __restrict__ tws,
    float* __restrict__ rowsum, float* __restrict__ diagsum,
    int* __restrict__ ticket, float* __restrict__ out)
{
    __shared__ __align__(16) unsigned char ldsB[8][16384];   // 128 KB ring
    __shared__ float wred[8];
    __shared__ int lastflag;

    const int tid  = threadIdx.x;
    const int lane = tid & 63;
    const int w    = tid >> 6;               // 0..7
    const int l15  = lane & 15;
    const int hi4  = lane >> 4;

    const int cc   = blockIdx.x & 15;        // col chunk (fast -> XCD locality)
    const int rb   = blockIdx.x >> 4;        // row block 0..15
    const int row0 = rb * 512 + w * 64;      // this wave's 64 rows
    const int col0 = cc * 512;
    const int tile0 = cc * 16;               // first 32-col tile of this chunk

    // stage tile st (16 KB, fragment-order = linear) into ring buffer bufi:
    // 512 threads x 2 x 16B insts.
#define STAGE(st, bufi)                                                      \
    {                                                                        \
        const unsigned char* gs = tws + (size_t)(tile0 + (st)) * 16384;      \
        _Pragma("unroll")                                                    \
        for (int it = 0; it < 2; ++it)                                       \
            __builtin_amdgcn_global_load_lds(                                \
                GLOBAL_U32(gs + (it * 512 + tid) * 16),                      \
                LDS_U32(&ldsB[bufi][(it * 512 + tid) * 16]), 16, 0, 0);      \
    }

    // prologue: pairs 0,1,2 (tiles 0..5) in flight = 12 insts/thread
    STAGE(0, 0); STAGE(1, 1);
    STAGE(2, 2); STAGE(3, 3);
    STAGE(4, 4); STAGE(5, 5);

    // ---- A fragments in registers: rows row0..row0+63, full K=256 ----
    // frag-order qws: byte = row0*512 + r*8192 + kst*1024 + lane*16
    // -> row = row0 + r*16 + (lane&15), k-run = (lane>>4), kst = k>>5
    bf16x8 a[4][8];
    {
        const unsigned char* abase = qws + (size_t)row0 * 512 + lane * 16;
#pragma unroll
        for (int r = 0; r < 4; ++r)
#pragma unroll
            for (int kst = 0; kst < 8; ++kst)
                a[r][kst] = *(const bf16x8*)(abase + r * 8192 + kst * 1024);
    }

    float rowacc[16] = {};
    float diagacc = 0.f;

    // process one 32-col tile t (2 col-frags x 8 k-steps, 64 MFMA, 8 chains)
    // MFMA cluster wrapped in setprio(1/0); immediate exp2 epilogue.
#define PROCESS_TILE(t)                                                      \
    {                                                                        \
        const unsigned char* bbuf = ldsB[(t) & 7] + lane * 16;               \
        f32x4 acc[4][2] = {};                                                \
        __builtin_amdgcn_s_setprio(1);                                       \
        _Pragma("unroll")                                                    \
        for (int kst = 0; kst < 8; ++kst) {                                  \
            bf16x8 b0 = *(const bf16x8*)(bbuf + kst * 1024);                 \
            bf16x8 b1 = *(const bf16x8*)(bbuf + 8192 + kst * 1024);          \
            _Pragma("unroll")                                                \
            for (int r4 = 0; r4 < 4; ++r4) {                                 \
                acc[r4][0] = __builtin_amdgcn_mfma_f32_16x16x32_bf16(        \
                                 a[r4][kst], b0, acc[r4][0], 0, 0, 0);       \
                acc[r4][1] = __builtin_amdgcn_mfma_f32_16x16x32_bf16(        \
                                 a[r4][kst], b1, acc[r4][1], 0, 0, 0);       \
            }                                                                \
        }                                                                    \
        __builtin_amdgcn_s_setprio(0);                                       \
        _Pragma("unroll")                                                    \
        for (int r4 = 0; r4 < 4; ++r4)                                       \
            _Pragma("unroll")                                                \
            for (int g2 = 0; g2 < 4; ++g2)                                   \
                rowacc[r4 * 4 + g2] += exp2f(acc[r4][0][g2] - QSCALE)        \
                                     + exp2f(acc[r4][1][g2] - QSCALE);       \
        const int c0t = col0 + (t) * 32;                                     \
        if (c0t == row0) {                                                   \
            _Pragma("unroll")                                                \
            for (int g2 = 0; g2 < 4; ++g2)                                   \
                if (l15 == hi4 * 4 + g2)                                     \
                    diagacc += acc[0][0][g2] + acc[1][1][g2];                \
        }                                                                    \
        if (c0t == row0 + 32) {                                              \
            _Pragma("unroll")                                                \
            for (int g2 = 0; g2 < 4; ++g2)                                   \
                if (l15 == hi4 * 4 + g2)                                     \
                    diagacc += acc[2][0][g2] + acc[3][1][g2];                \
        }                                                                    \
    }

    for (int r = 0; r < 8; ++r) {
        // counted wait: drain pair r (oldest 4 insts); pairs r+1, r+2
        // (8 insts) stay in flight. At r=0 this also drains the A-loads.
        __builtin_amdgcn_s_waitcnt(WAITCNT_VM8);
        __builtin_amdgcn_s_barrier();
        // stage pair r+3 into buffers (2r+6)&7,(2r+7)&7 -- last read in
        // round r-1. Tail rounds dummy-re-stage pair 7 (uniform vmcnt).
        const int p = (r + 3 < 8) ? r + 3 : 7;
        STAGE(2 * p,     (2 * r + 6) & 7);
        STAGE(2 * p + 1, (2 * r + 7) & 7);
        PROCESS_TILE(2 * r);
        PROCESS_TILE(2 * r + 1);
    }

    // ---- reduce across the 16 column-lanes of each group, then atomics ----
    // rowacc[rr]: row = row0 + (rr>>2)*16 + hi4*4 + (rr&3); xor-reduce over
    // the low 4 lane bits (16 lanes share a row).
#pragma unroll
    for (int rr = 0; rr < 16; ++rr) {
        float s = rowacc[rr];
        s += __shfl_xor(s, 1, 64);
        s += __shfl_xor(s, 2, 64);
        s += __shfl_xor(s, 4, 64);
        s += __shfl_xor(s, 8, 64);
        if (l15 == 0) {
            int grow = row0 + (rr >> 2) * 16 + hi4 * 4 + (rr & 3);
            atomicAdd(&rowsum[grow], s);
        }
    }

    float dsum = diagacc * LN2F;    // acc is z*log2e -> convert to z once
#pragma unroll
    for (int off = 32; off; off >>= 1) dsum += __shfl_xor(dsum, off, 64);
    if (lane == 0 && dsum != 0.f) atomicAdd(diagsum, dsum);

    // ---- ticket: last block computes the loss ----
    __syncthreads();
    if (tid == 0) {
        __threadfence();
        int old = __hip_atomic_fetch_add(ticket, 1, __ATOMIC_ACQ_REL,
                                         __HIP_MEMORY_SCOPE_AGENT);
        lastflag = (old == GRID_GEMM - 1);
    }
    __syncthreads();
    if (!lastflag) return;

    float lsum = 0.f;
    for (int rr = tid; rr < B_DIM; rr += 512) {
        float rs = __hip_atomic_load(&rowsum[rr], __ATOMIC_RELAXED,
                                     __HIP_MEMORY_SCOPE_AGENT);
        lsum += __logf(rs);
    }
#pragma unroll
    for (int off = 32; off; off >>= 1) lsum += __shfl_xor(lsum, off, 64);
    if (lane == 0) wred[w] = lsum;
    __syncthreads();
    if (tid == 0) {
        float total = wred[0] + wred[1] + wred[2] + wred[3]
                    + wred[4] + wred[5] + wred[6] + wred[7]
                    + (float)B_DIM * INV_T   // + M per row
                    - __hip_atomic_load(diagsum, __ATOMIC_RELAXED,
                                        __HIP_MEMORY_SCOPE_AGENT);
        out[0] = total / (float)B_DIM;
    }
}

extern "C" void kernel_launch(void* const* d_in, const int* in_sizes, int n_in,
                              void* d_out, int out_size, void* d_ws, size_t ws_size,
                              hipStream_t stream)
{
    const float* h = (const float*)d_in[0];
    const float* r = (const float*)d_in[1];
    const float* t = (const float*)d_in[2];

    unsigned char* ws = (unsigned char*)d_ws;
    unsigned short* qws = (unsigned short*)ws;                        // 4 MB (frag order, pre-scaled)
    unsigned short* tws = (unsigned short*)(ws + 4u * 1024 * 1024);   // 4 MB (frag order)
    float* rowsum  = (float*)(ws + 8u * 1024 * 1024);                 // 32 KB
    float* diagsum = (float*)(ws + 8u * 1024 * 1024 + 32u * 1024);
    int*   ticket  = (int*)  (ws + 8u * 1024 * 1024 + 32u * 1024 + 16);

    norm_kernel<<<1024, 256, 0, stream>>>(h, r, t, qws, tws, rowsum, diagsum, ticket);
    gemm_lse_kernel<<<GRID_GEMM, 512, 0, stream>>>(
        (const unsigned char*)qws, (const unsigned char*)tws,
        rowsum, diagsum, ticket, (float*)d_out);
}

// Round 18
// 118.855 us; speedup vs baseline: 1.1557x; 1.0613x over previous
//
#include <hip/hip_runtime.h>
#include <hip/hip_bf16.h>

#define B_DIM 8192
#define D_DIM 256
#define GRID_GEMM 256
#define NT 16   // 32-col tiles per block (512 cols per block)

constexpr float INV_T  = 14.285714285714286f;   // 1/0.07; the logsumexp shift M
// q pre-scaled by INV_T*log2(e): acc = z*log2(e); exp(z-M) = exp2(acc - QS)
constexpr float QSCALE = 20.609929155556605f;   // INV_T * log2(e)
constexpr float LN2F   = 0.6931471805599453f;

typedef __bf16 bf16x8 __attribute__((ext_vector_type(8)));
typedef float  f32x4  __attribute__((ext_vector_type(4)));

#define GLOBAL_U32(p) ((const __attribute__((address_space(1))) unsigned int*)(p))
#define LDS_U32(p)    ((__attribute__((address_space(3))) unsigned int*)(p))

// s_waitcnt imm (gfx9): vm[3:0]=bits3:0, exp=bits6:4, lgkm=bits11:8, vm[5:4]=bits15:14
// vmcnt(8), expcnt/lgkmcnt = no-wait:
#define WAITCNT_VM8 0x0F78

__device__ inline unsigned short f2bf(float f) {
    union { float f; unsigned u; } x; x.f = f;
    unsigned r = x.u + 0x7fffu + ((x.u >> 16) & 1u);  // RNE
    return (unsigned short)(r >> 16);
}

// Kernel 1: q = normalize(h+r) * QSCALE, t = normalize(t); BOTH stored in
// 16x16x32-MFMA FRAGMENT order: 16B-slot ((row>>4)*8 + (k>>5))*64 +
// ((k>>3)&3)*16 + (row&15) holds k-run [k&~7 .. +8). GEMM lane l reads
// slot (l>>4)*16 + (l&15): row=(l&15), k-run=(l>>4) -- coalesced 1KB/inst.
// (verified R13/R15/R17). Block 0 additionally zeroes rowsum/diagsum/ticket.
__global__ __launch_bounds__(256) void norm_kernel(
    const float* __restrict__ h, const float* __restrict__ r,
    const float* __restrict__ t,
    unsigned short* __restrict__ qws, unsigned short* __restrict__ tws,
    float* __restrict__ rowsum, float* __restrict__ diagsum, int* __restrict__ ticket)
{
    if (blockIdx.x == 0) {
        float4* rs4 = (float4*)rowsum;
#pragma unroll
        for (int i = 0; i < 8; ++i)
            rs4[threadIdx.x * 8 + i] = make_float4(0.f, 0.f, 0.f, 0.f);
        if (threadIdx.x == 0) { *diagsum = 0.f; *ticket = 0; }
    }

    const int wave = threadIdx.x >> 6;
    const int lane = threadIdx.x & 63;
    const int wg   = blockIdx.x * 4 + wave;      // 0..4095, 2 rows each

    // fragment store coords for this lane (k = 4*lane + j'):
    const int kst  = lane >> 3;          // k>>5
    const int krun = (lane >> 1) & 3;    // (k>>3)&3
    const int sub8 = lane & 1;           // (k>>2)&1 within the 8-run

#pragma unroll
    for (int i = 0; i < 2; ++i) {
        const int row = wg * 2 + i;              // 0..8191
        const size_t slot16 = ((size_t)((row >> 4) * 8 + kst) * 64
                               + (size_t)(krun * 16 + (row & 15)));
        // ---- q = normalize(h+r) * QSCALE ----
        {
            float4 a = ((const float4*)h)[row * 64 + lane];
            float4 b = ((const float4*)r)[row * 64 + lane];
            float4 v = make_float4(a.x + b.x, a.y + b.y, a.z + b.z, a.w + b.w);
            float s = v.x * v.x + v.y * v.y + v.z * v.z + v.w * v.w;
#pragma unroll
            for (int off = 32; off; off >>= 1) s += __shfl_xor(s, off, 64);
            float scale = QSCALE / fmaxf(sqrtf(s), 1e-12f);
            ushort4 o;
            o.x = f2bf(v.x * scale); o.y = f2bf(v.y * scale);
            o.z = f2bf(v.z * scale); o.w = f2bf(v.w * scale);
            *(ushort4*)((unsigned char*)qws + slot16 * 16 + sub8 * 8) = o;
        }
        // ---- t = normalize(t) ----
        {
            float4 v = ((const float4*)t)[row * 64 + lane];
            float s = v.x * v.x + v.y * v.y + v.z * v.z + v.w * v.w;
#pragma unroll
            for (int off = 32; off; off >>= 1) s += __shfl_xor(s, off, 64);
            float scale = 1.0f / fmaxf(sqrtf(s), 1e-12f);
            ushort4 o;
            o.x = f2bf(v.x * scale); o.y = f2bf(v.y * scale);
            o.z = f2bf(v.z * scale); o.w = f2bf(v.w * scale);
            *(ushort4*)((unsigned char*)tws + slot16 * 16 + sub8 * 8) = o;
        }
    }
}

// Kernel 2: R15's verified deep-prefetch skeleton EXACTLY (512-thread block,
// 1/CU, ring-8 x 16 KB = 128 KB, prefetch distance 3 pairs, counted
// vmcnt(8), one barrier per round, single acc set, immediate epilogue, NO
// setprio). R17's regression isolated to libm exp2f (guarded expansion:
// VALUBusy 22->31%); fixed with the RAW builtin __builtin_amdgcn_exp2f
// (v_exp_f32, compiler-managed TRANS hazards). Epilogue is now v_sub+v_exp
// per element -- one v_mul cheaper than R15's __expf path. Everything else
// (MFMA 16x16x32 8-chain, a[4][8] in regs, frag-order linear staging/reads,
// ring algebra, dummy tail) = R15 verbatim; q pre-scaled so acc = z*log2e.
__global__ __launch_bounds__(512, 2) void gemm_lse_kernel(
    const unsigned char* __restrict__ qws, const unsigned char* __restrict__ tws,
    float* __restrict__ rowsum, float* __restrict__ diagsum,
    int* __restrict__ ticket, float* __restrict__ out)
{
    __shared__ __align__(16) unsigned char ldsB[8][16384];   // 128 KB ring
    __shared__ float wred[8];
    __shared__ int lastflag;

    const int tid  = threadIdx.x;
    const int lane = tid & 63;
    const int w    = tid >> 6;               // 0..7
    const int l15  = lane & 15;
    const int hi4  = lane >> 4;

    const int cc   = blockIdx.x & 15;        // col chunk (fast -> XCD locality)
    const int rb   = blockIdx.x >> 4;        // row block 0..15
    const int row0 = rb * 512 + w * 64;      // this wave's 64 rows
    const int col0 = cc * 512;
    const int tile0 = cc * 16;               // first 32-col tile of this chunk

    // stage tile st (16 KB, fragment-order = linear) into ring buffer bufi:
    // 512 threads x 2 x 16B insts.
#define STAGE(st, bufi)                                                      \
    {                                                                        \
        const unsigned char* gs = tws + (size_t)(tile0 + (st)) * 16384;      \
        _Pragma("unroll")                                                    \
        for (int it = 0; it < 2; ++it)                                       \
            __builtin_amdgcn_global_load_lds(                                \
                GLOBAL_U32(gs + (it * 512 + tid) * 16),                      \
                LDS_U32(&ldsB[bufi][(it * 512 + tid) * 16]), 16, 0, 0);      \
    }

    // prologue: pairs 0,1,2 (tiles 0..5) in flight = 12 insts/thread
    STAGE(0, 0); STAGE(1, 1);
    STAGE(2, 2); STAGE(3, 3);
    STAGE(4, 4); STAGE(5, 5);

    // ---- A fragments in registers: rows row0..row0+63, full K=256 ----
    // frag-order qws: byte = row0*512 + r*8192 + kst*1024 + lane*16
    // -> row = row0 + r*16 + (lane&15), k-run = (lane>>4), kst = k>>5
    bf16x8 a[4][8];
    {
        const unsigned char* abase = qws + (size_t)row0 * 512 + lane * 16;
#pragma unroll
        for (int r = 0; r < 4; ++r)
#pragma unroll
            for (int kst = 0; kst < 8; ++kst)
                a[r][kst] = *(const bf16x8*)(abase + r * 8192 + kst * 1024);
    }

    float rowacc[16] = {};
    float diagacc = 0.f;

    // process one 32-col tile t (2 col-frags x 8 k-steps, 64 MFMA, 8 chains)
    // with immediate epilogue: raw v_exp_f32 via __builtin_amdgcn_exp2f.
#define PROCESS_TILE(t)                                                      \
    {                                                                        \
        const unsigned char* bbuf = ldsB[(t) & 7] + lane * 16;               \
        f32x4 acc[4][2] = {};                                                \
        _Pragma("unroll")                                                    \
        for (int kst = 0; kst < 8; ++kst) {                                  \
            bf16x8 b0 = *(const bf16x8*)(bbuf + kst * 1024);                 \
            bf16x8 b1 = *(const bf16x8*)(bbuf + 8192 + kst * 1024);          \
            _Pragma("unroll")                                                \
            for (int r4 = 0; r4 < 4; ++r4) {                                 \
                acc[r4][0] = __builtin_amdgcn_mfma_f32_16x16x32_bf16(        \
                                 a[r4][kst], b0, acc[r4][0], 0, 0, 0);       \
                acc[r4][1] = __builtin_amdgcn_mfma_f32_16x16x32_bf16(        \
                                 a[r4][kst], b1, acc[r4][1], 0, 0, 0);       \
            }                                                                \
        }                                                                    \
        _Pragma("unroll")                                                    \
        for (int r4 = 0; r4 < 4; ++r4)                                       \
            _Pragma("unroll")                                                \
            for (int g2 = 0; g2 < 4; ++g2)                                   \
                rowacc[r4 * 4 + g2] +=                                       \
                    __builtin_amdgcn_exp2f(acc[r4][0][g2] - QSCALE)          \
                  + __builtin_amdgcn_exp2f(acc[r4][1][g2] - QSCALE);         \
        const int c0t = col0 + (t) * 32;                                     \
        if (c0t == row0) {                                                   \
            _Pragma("unroll")                                                \
            for (int g2 = 0; g2 < 4; ++g2)                                   \
                if (l15 == hi4 * 4 + g2)                                     \
                    diagacc += acc[0][0][g2] + acc[1][1][g2];                \
        }                                                                    \
        if (c0t == row0 + 32) {                                              \
            _Pragma("unroll")                                                \
            for (int g2 = 0; g2 < 4; ++g2)                                   \
                if (l15 == hi4 * 4 + g2)                                     \
                    diagacc += acc[2][0][g2] + acc[3][1][g2];                \
        }                                                                    \
    }

    for (int r = 0; r < 8; ++r) {
        // counted wait: drain pair r (oldest 4 insts); pairs r+1, r+2
        // (8 insts) stay in flight. At r=0 this also drains the A-loads.
        __builtin_amdgcn_s_waitcnt(WAITCNT_VM8);
        __builtin_amdgcn_s_barrier();
        // stage pair r+3 into buffers (2r+6)&7,(2r+7)&7 -- last read in
        // round r-1. Tail rounds dummy-re-stage pair 7 (uniform vmcnt).
        const int p = (r + 3 < 8) ? r + 3 : 7;
        STAGE(2 * p,     (2 * r + 6) & 7);
        STAGE(2 * p + 1, (2 * r + 7) & 7);
        PROCESS_TILE(2 * r);
        PROCESS_TILE(2 * r + 1);
    }

    // ---- reduce across the 16 column-lanes of each group, then atomics ----
    // rowacc[rr]: row = row0 + (rr>>2)*16 + hi4*4 + (rr&3); xor-reduce over
    // the low 4 lane bits (16 lanes share a row).
#pragma unroll
    for (int rr = 0; rr < 16; ++rr) {
        float s = rowacc[rr];
        s += __shfl_xor(s, 1, 64);
        s += __shfl_xor(s, 2, 64);
        s += __shfl_xor(s, 4, 64);
        s += __shfl_xor(s, 8, 64);
        if (l15 == 0) {
            int grow = row0 + (rr >> 2) * 16 + hi4 * 4 + (rr & 3);
            atomicAdd(&rowsum[grow], s);
        }
    }

    float dsum = diagacc * LN2F;    // acc is z*log2e -> convert to z once
#pragma unroll
    for (int off = 32; off; off >>= 1) dsum += __shfl_xor(dsum, off, 64);
    if (lane == 0 && dsum != 0.f) atomicAdd(diagsum, dsum);

    // ---- ticket: last block computes the loss ----
    __syncthreads();
    if (tid == 0) {
        __threadfence();
        int old = __hip_atomic_fetch_add(ticket, 1, __ATOMIC_ACQ_REL,
                                         __HIP_MEMORY_SCOPE_AGENT);
        lastflag = (old == GRID_GEMM - 1);
    }
    __syncthreads();
    if (!lastflag) return;

    float lsum = 0.f;
    for (int rr = tid; rr < B_DIM; rr += 512) {
        float rs = __hip_atomic_load(&rowsum[rr], __ATOMIC_RELAXED,
                                     __HIP_MEMORY_SCOPE_AGENT);
        lsum += __logf(rs);
    }
#pragma unroll
    for (int off = 32; off; off >>= 1) lsum += __shfl_xor(lsum, off, 64);
    if (lane == 0) wred[w] = lsum;
    __syncthreads();
    if (tid == 0) {
        float total = wred[0] + wred[1] + wred[2] + wred[3]
                    + wred[4] + wred[5] + wred[6] + wred[7]
                    + (float)B_DIM * INV_T   // + M per row
                    - __hip_atomic_load(diagsum, __ATOMIC_RELAXED,
                                        __HIP_MEMORY_SCOPE_AGENT);
        out[0] = total / (float)B_DIM;
    }
}

extern "C" void kernel_launch(void* const* d_in, const int* in_sizes, int n_in,
                              void* d_out, int out_size, void* d_ws, size_t ws_size,
                              hipStream_t stream)
{
    const float* h = (const float*)d_in[0];
    const float* r = (const float*)d_in[1];
    const float* t = (const float*)d_in[2];

    unsigned char* ws = (unsigned char*)d_ws;
    unsigned short* qws = (unsigned short*)ws;                        // 4 MB (frag order, pre-scaled)
    unsigned short* tws = (unsigned short*)(ws + 4u * 1024 * 1024);   // 4 MB (frag order)
    float* rowsum  = (float*)(ws + 8u * 1024 * 1024);                 // 32 KB
    float* diagsum = (float*)(ws + 8u * 1024 * 1024 + 32u * 1024);
    int*   ticket  = (int*)  (ws + 8u * 1024 * 1024 + 32u * 1024 + 16);

    norm_kernel<<<1024, 256, 0, stream>>>(h, r, t, qws, tws, rowsum, diagsum, ticket);
    gemm_lse_kernel<<<GRID_GEMM, 512, 0, stream>>>(
        (const unsigned char*)qws, (const unsigned char*)tws,
        rowsum, diagsum, ticket, (float*)d_out);
}

// Round 19
// 118.204 us; speedup vs baseline: 1.1621x; 1.0055x over previous
//
#include <hip/hip_runtime.h>
#include <hip/hip_bf16.h>

#define B_DIM 8192
#define D_DIM 256
#define GRID_GEMM 256
#define NT 16   // 32-col tiles per block (512 cols per block)

constexpr float INV_T  = 14.285714285714286f;   // 1/0.07; the logsumexp shift M
// q pre-scaled by INV_T*log2(e): acc = z*log2(e); exp(z-M) = exp2(acc - QS)
constexpr float QSCALE = 20.609929155556605f;   // INV_T * log2(e)
constexpr float LN2F   = 0.6931471805599453f;

typedef __bf16 bf16x8 __attribute__((ext_vector_type(8)));
typedef float  f32x4  __attribute__((ext_vector_type(4)));

#define GLOBAL_U32(p) ((const __attribute__((address_space(1))) unsigned int*)(p))
#define LDS_U32(p)    ((__attribute__((address_space(3))) unsigned int*)(p))

// s_waitcnt imm (gfx9): vm[3:0]=bits3:0, exp=bits6:4, lgkm=bits11:8, vm[5:4]=bits15:14
// vmcnt(8), expcnt/lgkmcnt = no-wait:
#define WAITCNT_VM8 0x0F78

__device__ inline unsigned short f2bf(float f) {
    union { float f; unsigned u; } x; x.f = f;
    unsigned r = x.u + 0x7fffu + ((x.u >> 16) & 1u);  // RNE
    return (unsigned short)(r >> 16);
}

// Kernel 1: q = normalize(h+r) * QSCALE, t = normalize(t); BOTH stored in
// 16x16x32-MFMA FRAGMENT order: 16B-slot ((row>>4)*8 + (k>>5))*64 +
// ((k>>3)&3)*16 + (row&15) holds k-run [k&~7 .. +8). GEMM lane l reads
// slot (l>>4)*16 + (l&15): row=(l&15), k-run=(l>>4) -- coalesced 1KB/inst.
// (verified R13/R15/R17/R18). Block 0 also zeroes rowsum/diagsum/ticket.
__global__ __launch_bounds__(256) void norm_kernel(
    const float* __restrict__ h, const float* __restrict__ r,
    const float* __restrict__ t,
    unsigned short* __restrict__ qws, unsigned short* __restrict__ tws,
    float* __restrict__ rowsum, float* __restrict__ diagsum, int* __restrict__ ticket)
{
    if (blockIdx.x == 0) {
        float4* rs4 = (float4*)rowsum;
#pragma unroll
        for (int i = 0; i < 8; ++i)
            rs4[threadIdx.x * 8 + i] = make_float4(0.f, 0.f, 0.f, 0.f);
        if (threadIdx.x == 0) { *diagsum = 0.f; *ticket = 0; }
    }

    const int wave = threadIdx.x >> 6;
    const int lane = threadIdx.x & 63;
    const int wg   = blockIdx.x * 4 + wave;      // 0..4095, 2 rows each

    // fragment store coords for this lane (k = 4*lane + j'):
    const int kst  = lane >> 3;          // k>>5
    const int krun = (lane >> 1) & 3;    // (k>>3)&3
    const int sub8 = lane & 1;           // (k>>2)&1 within the 8-run

#pragma unroll
    for (int i = 0; i < 2; ++i) {
        const int row = wg * 2 + i;              // 0..8191
        const size_t slot16 = ((size_t)((row >> 4) * 8 + kst) * 64
                               + (size_t)(krun * 16 + (row & 15)));
        // ---- q = normalize(h+r) * QSCALE ----
        {
            float4 a = ((const float4*)h)[row * 64 + lane];
            float4 b = ((const float4*)r)[row * 64 + lane];
            float4 v = make_float4(a.x + b.x, a.y + b.y, a.z + b.z, a.w + b.w);
            float s = v.x * v.x + v.y * v.y + v.z * v.z + v.w * v.w;
#pragma unroll
            for (int off = 32; off; off >>= 1) s += __shfl_xor(s, off, 64);
            float scale = QSCALE / fmaxf(sqrtf(s), 1e-12f);
            ushort4 o;
            o.x = f2bf(v.x * scale); o.y = f2bf(v.y * scale);
            o.z = f2bf(v.z * scale); o.w = f2bf(v.w * scale);
            *(ushort4*)((unsigned char*)qws + slot16 * 16 + sub8 * 8) = o;
        }
        // ---- t = normalize(t) ----
        {
            float4 v = ((const float4*)t)[row * 64 + lane];
            float s = v.x * v.x + v.y * v.y + v.z * v.z + v.w * v.w;
#pragma unroll
            for (int off = 32; off; off >>= 1) s += __shfl_xor(s, off, 64);
            float scale = 1.0f / fmaxf(sqrtf(s), 1e-12f);
            ushort4 o;
            o.x = f2bf(v.x * scale); o.y = f2bf(v.y * scale);
            o.z = f2bf(v.z * scale); o.w = f2bf(v.w * scale);
            *(ushort4*)((unsigned char*)tws + slot16 * 16 + sub8 * 8) = o;
        }
    }
}

// Kernel 2: R18 EXACTLY (512-thread block, 1/CU, ring-8 x 16 KB = 128 KB,
// prefetch distance 3 pairs, counted vmcnt(8), one barrier per round,
// single acc set, immediate raw-exp2 epilogue) + ONE isolated change:
// T5 s_setprio(1/0) around each tile's MFMA cluster. R17 could not
// isolate setprio (confounded with the libm-exp2f regression). Evidence
// regime: m218b/m224 measured +21-39% for setprio on counted-vmcnt
// deep-pipeline GEMMs (this structure); m190's null was lockstep-shallow.
// Register- and structure-neutral; if within noise, the lever ledger is
// complete and R18 is the floor.
__global__ __launch_bounds__(512, 2) void gemm_lse_kernel(
    const unsigned char* __restrict__ qws, const unsigned char* __restrict__ tws,
    float* __restrict__ rowsum, float* __restrict__ diagsum,
    int* __restrict__ ticket, float* __restrict__ out)
{
    __shared__ __align__(16) unsigned char ldsB[8][16384];   // 128 KB ring
    __shared__ float wred[8];
    __shared__ int lastflag;

    const int tid  = threadIdx.x;
    const int lane = tid & 63;
    const int w    = tid >> 6;               // 0..7
    const int l15  = lane & 15;
    const int hi4  = lane >> 4;

    const int cc   = blockIdx.x & 15;        // col chunk (fast -> XCD locality)
    const int rb   = blockIdx.x >> 4;        // row block 0..15
    const int row0 = rb * 512 + w * 64;      // this wave's 64 rows
    const int col0 = cc * 512;
    const int tile0 = cc * 16;               // first 32-col tile of this chunk

    // stage tile st (16 KB, fragment-order = linear) into ring buffer bufi:
    // 512 threads x 2 x 16B insts.
#define STAGE(st, bufi)                                                      \
    {                                                                        \
        const unsigned char* gs = tws + (size_t)(tile0 + (st)) * 16384;      \
        _Pragma("unroll")                                                    \
        for (int it = 0; it < 2; ++it)                                       \
            __builtin_amdgcn_global_load_lds(                                \
                GLOBAL_U32(gs + (it * 512 + tid) * 16),                      \
                LDS_U32(&ldsB[bufi][(it * 512 + tid) * 16]), 16, 0, 0);      \
    }

    // prologue: pairs 0,1,2 (tiles 0..5) in flight = 12 insts/thread
    STAGE(0, 0); STAGE(1, 1);
    STAGE(2, 2); STAGE(3, 3);
    STAGE(4, 4); STAGE(5, 5);

    // ---- A fragments in registers: rows row0..row0+63, full K=256 ----
    // frag-order qws: byte = row0*512 + r*8192 + kst*1024 + lane*16
    // -> row = row0 + r*16 + (lane&15), k-run = (lane>>4), kst = k>>5
    bf16x8 a[4][8];
    {
        const unsigned char* abase = qws + (size_t)row0 * 512 + lane * 16;
#pragma unroll
        for (int r = 0; r < 4; ++r)
#pragma unroll
            for (int kst = 0; kst < 8; ++kst)
                a[r][kst] = *(const bf16x8*)(abase + r * 8192 + kst * 1024);
    }

    float rowacc[16] = {};
    float diagacc = 0.f;

    // process one 32-col tile t (2 col-frags x 8 k-steps, 64 MFMA, 8 chains)
    // MFMA cluster wrapped in setprio(1/0); immediate raw-exp2 epilogue.
#define PROCESS_TILE(t)                                                      \
    {                                                                        \
        const unsigned char* bbuf = ldsB[(t) & 7] + lane * 16;               \
        f32x4 acc[4][2] = {};                                                \
        __builtin_amdgcn_s_setprio(1);                                       \
        _Pragma("unroll")                                                    \
        for (int kst = 0; kst < 8; ++kst) {                                  \
            bf16x8 b0 = *(const bf16x8*)(bbuf + kst * 1024);                 \
            bf16x8 b1 = *(const bf16x8*)(bbuf + 8192 + kst * 1024);          \
            _Pragma("unroll")                                                \
            for (int r4 = 0; r4 < 4; ++r4) {                                 \
                acc[r4][0] = __builtin_amdgcn_mfma_f32_16x16x32_bf16(        \
                                 a[r4][kst], b0, acc[r4][0], 0, 0, 0);       \
                acc[r4][1] = __builtin_amdgcn_mfma_f32_16x16x32_bf16(        \
                                 a[r4][kst], b1, acc[r4][1], 0, 0, 0);       \
            }                                                                \
        }                                                                    \
        __builtin_amdgcn_s_setprio(0);                                       \
        _Pragma("unroll")                                                    \
        for (int r4 = 0; r4 < 4; ++r4)                                       \
            _Pragma("unroll")                                                \
            for (int g2 = 0; g2 < 4; ++g2)                                   \
                rowacc[r4 * 4 + g2] +=                                       \
                    __builtin_amdgcn_exp2f(acc[r4][0][g2] - QSCALE)          \
                  + __builtin_amdgcn_exp2f(acc[r4][1][g2] - QSCALE);         \
        const int c0t = col0 + (t) * 32;                                     \
        if (c0t == row0) {                                                   \
            _Pragma("unroll")                                                \
            for (int g2 = 0; g2 < 4; ++g2)                                   \
                if (l15 == hi4 * 4 + g2)                                     \
                    diagacc += acc[0][0][g2] + acc[1][1][g2];                \
        }                                                                    \
        if (c0t == row0 + 32) {                                              \
            _Pragma("unroll")                                                \
            for (int g2 = 0; g2 < 4; ++g2)                                   \
                if (l15 == hi4 * 4 + g2)                                     \
                    diagacc += acc[2][0][g2] + acc[3][1][g2];                \
        }                                                                    \
    }

    for (int r = 0; r < 8; ++r) {
        // counted wait: drain pair r (oldest 4 insts); pairs r+1, r+2
        // (8 insts) stay in flight. At r=0 this also drains the A-loads.
        __builtin_amdgcn_s_waitcnt(WAITCNT_VM8);
        __builtin_amdgcn_s_barrier();
        // stage pair r+3 into buffers (2r+6)&7,(2r+7)&7 -- last read in
        // round r-1. Tail rounds dummy-re-stage pair 7 (uniform vmcnt).
        const int p = (r + 3 < 8) ? r + 3 : 7;
        STAGE(2 * p,     (2 * r + 6) & 7);
        STAGE(2 * p + 1, (2 * r + 7) & 7);
        PROCESS_TILE(2 * r);
        PROCESS_TILE(2 * r + 1);
    }

    // ---- reduce across the 16 column-lanes of each group, then atomics ----
    // rowacc[rr]: row = row0 + (rr>>2)*16 + hi4*4 + (rr&3); xor-reduce over
    // the low 4 lane bits (16 lanes share a row).
#pragma unroll
    for (int rr = 0; rr < 16; ++rr) {
        float s = rowacc[rr];
        s += __shfl_xor(s, 1, 64);
        s += __shfl_xor(s, 2, 64);
        s += __shfl_xor(s, 4, 64);
        s += __shfl_xor(s, 8, 64);
        if (l15 == 0) {
            int grow = row0 + (rr >> 2) * 16 + hi4 * 4 + (rr & 3);
            atomicAdd(&rowsum[grow], s);
        }
    }

    float dsum = diagacc * LN2F;    // acc is z*log2e -> convert to z once
#pragma unroll
    for (int off = 32; off; off >>= 1) dsum += __shfl_xor(dsum, off, 64);
    if (lane == 0 && dsum != 0.f) atomicAdd(diagsum, dsum);

    // ---- ticket: last block computes the loss ----
    __syncthreads();
    if (tid == 0) {
        __threadfence();
        int old = __hip_atomic_fetch_add(ticket, 1, __ATOMIC_ACQ_REL,
                                         __HIP_MEMORY_SCOPE_AGENT);
        lastflag = (old == GRID_GEMM - 1);
    }
    __syncthreads();
    if (!lastflag) return;

    float lsum = 0.f;
    for (int rr = tid; rr < B_DIM; rr += 512) {
        float rs = __hip_atomic_load(&rowsum[rr], __ATOMIC_RELAXED,
                                     __HIP_MEMORY_SCOPE_AGENT);
        lsum += __logf(rs);
    }
#pragma unroll
    for (int off = 32; off; off >>= 1) lsum += __shfl_xor(lsum, off, 64);
    if (lane == 0) wred[w] = lsum;
    __syncthreads();
    if (tid == 0) {
        float total = wred[0] + wred[1] + wred[2] + wred[3]
                    + wred[4] + wred[5] + wred[6] + wred[7]
                    + (float)B_DIM * INV_T   // + M per row
                    - __hip_atomic_load(diagsum, __ATOMIC_RELAXED,
                                        __HIP_MEMORY_SCOPE_AGENT);
        out[0] = total / (float)B_DIM;
    }
}

extern "C" void kernel_launch(void* const* d_in, const int* in_sizes, int n_in,
                              void* d_out, int out_size, void* d_ws, size_t ws_size,
                              hipStream_t stream)
{
    const float* h = (const float*)d_in[0];
    const float* r = (const float*)d_in[1];
    const float* t = (const float*)d_in[2];

    unsigned char* ws = (unsigned char*)d_ws;
    unsigned short* qws = (unsigned short*)ws;                        // 4 MB (frag order, pre-scaled)
    unsigned short* tws = (unsigned short*)(ws + 4u * 1024 * 1024);   // 4 MB (frag order)
    float* rowsum  = (float*)(ws + 8u * 1024 * 1024);                 // 32 KB
    float* diagsum = (float*)(ws + 8u * 1024 * 1024 + 32u * 1024);
    int*   ticket  = (int*)  (ws + 8u * 1024 * 1024 + 32u * 1024 + 16);

    norm_kernel<<<1024, 256, 0, stream>>>(h, r, t, qws, tws, rowsum, diagsum, ticket);
    gemm_lse_kernel<<<GRID_GEMM, 512, 0, stream>>>(
        (const unsigned char*)qws, (const unsigned char*)tws,
        rowsum, diagsum, ticket, (float*)d_out);
}